// Round 13
// baseline (210.850 us; speedup 1.0000x reference)
//
#include <hip/hip_runtime.h>
#include <hip/hip_bf16.h>

// Problem constants
#define B_    8
#define F_    16
#define NP_   196
#define SEQ_  3137        // 1 + F_*NP_
#define H_    8
#define DH_   64
#define BH_   64          // B_*H_
#define M_    25096       // B_*SEQ_
#define DIM_  512
#define NQKV_ 1536

typedef _Float16 half8_t __attribute__((ext_vector_type(8)));
typedef _Float16 half4_t __attribute__((ext_vector_type(4)));
typedef float f32x4 __attribute__((ext_vector_type(4)));

// workspace byte offsets
#define XH_OFF     ((size_t)0)                    // [M][512] f16
#define WQKVT_OFF  ((size_t)25821184)             // [1536][512] f16
#define WOUTT_OFF  ((size_t)27394048)             // [512][512]  f16
#define QH_OFF     ((size_t)27918336)             // [64][3137][64] f16
#define KH_OFF     ((size_t)53616640)
#define VH_OFF     ((size_t)79314944)
#define ATTNH_OFF  ((size_t)105013248)            // [M][512] f16
#define CLSP_OFF   XH_OFF                         // aliases xh (dead after qkv)

__device__ __forceinline__ void load_lds16(const _Float16* g, _Float16* l) {
  __builtin_amdgcn_global_load_lds(
      (const __attribute__((address_space(1))) void*)g,
      (__attribute__((address_space(3))) void*)l, 16, 0, 0);
}

// bijective XCD-chunk swizzle (m204)
__device__ __forceinline__ int xcd_swz(int orig, int nwg) {
  int q = nwg >> 3, r = nwg & 7;
  int x = orig & 7, j = orig >> 3;
  return (x < r ? x * (q + 1) : r * (q + 1) + (x - r) * q) + j;
}

// ---------------------------------------------------------------------------
// prep: blocks 0..1023 = weight transposes (fp32->f16 [C][512]);
//       blocks 1024..3071 = x fp32->f16 convert.
// ---------------------------------------------------------------------------
__global__ __launch_bounds__(256) void prep_kernel(
    const float* __restrict__ x, _Float16* __restrict__ xh,
    const float* __restrict__ wqkv, _Float16* __restrict__ wqkvT,
    const float* __restrict__ wout, _Float16* __restrict__ woutT) {
  if (blockIdx.x < 1024) {
    __shared__ float tile[32][33];
    int id = blockIdx.x;
    int xb = id & 15, by = id >> 4;
    const float* in; _Float16* out; int C;
    if (by < 48) { in = wqkv; out = wqkvT; C = NQKV_; }
    else         { in = wout; out = woutT; C = DIM_;  by -= 48; }
    const int r0 = xb * 32, c0 = by * 32;
    const int lr = threadIdx.x >> 5, lc = threadIdx.x & 31;
#pragma unroll
    for (int p = 0; p < 4; ++p) {
      int r = p * 8 + lr;
      tile[r][lc] = in[(size_t)(r0 + r) * C + c0 + lc];
    }
    __syncthreads();
#pragma unroll
    for (int p = 0; p < 4; ++p) {
      int rr = p * 8 + lr;
      out[(size_t)(c0 + rr) * DIM_ + r0 + lc] = (_Float16)tile[lc][rr];
    }
    return;
  }
  const int id = blockIdx.x - 1024;  // 0..2047
  const size_t n8 = (size_t)M_ * DIM_ / 8;
  for (size_t i = (size_t)id * 256 + threadIdx.x; i < n8;
       i += (size_t)2048 * 256) {
    float4 a = ((const float4*)x)[2 * i];
    float4 b = ((const float4*)x)[2 * i + 1];
    half8_t h;
    h[0] = (_Float16)a.x; h[1] = (_Float16)a.y; h[2] = (_Float16)a.z; h[3] = (_Float16)a.w;
    h[4] = (_Float16)b.x; h[5] = (_Float16)b.y; h[6] = (_Float16)b.z; h[7] = (_Float16)b.w;
    ((half8_t*)xh)[i] = h;
  }
}

// ---------------------------------------------------------------------------
// 256x128 block tile, BK=64, 256 threads = 4 waves (2M x 2N), wave tile
// 128x64 (acc 8x4 frags). Per kk: 8 A-reads + 4 B-reads -> 32 MFMA
// (2.67 MFMA/ds_read). LDS XOR-swizzled: linear global_load_lds dest +
// pre-swizzled global source col; frag reads XOR (row&7)<<3.
// ---------------------------------------------------------------------------
__device__ __forceinline__ void gemm_mainloop_f16_w128(
    const _Float16* __restrict__ A, const _Float16* __restrict__ Bt,
    int m0, int n0, int maxA, _Float16* As, _Float16* Bs, f32x4 acc[8][4]) {
  const int tid = threadIdx.x;
  const int w = tid >> 6, lane = tid & 63;
  const int wm = w >> 1, wn = w & 1;
  const int lrow = lane & 15;
  const int g = lane >> 4;
  const int sw = lane & 7;

  for (int k0 = 0; k0 < DIM_; k0 += 64) {
#pragma unroll
    for (int i = 0; i < 8; ++i) {          // A: 256 rows x 64 cols
      int c = i * 256 + tid;
      int row = c >> 3, s = c & 7;
      int ra = min(m0 + row, maxA);
      load_lds16(A + (size_t)ra * DIM_ + k0 + ((s ^ (row & 7)) << 3),
                 As + (i * 256 + (tid & 192)) * 8);
    }
#pragma unroll
    for (int i = 0; i < 4; ++i) {          // B: 128 rows x 64 cols
      int c = i * 256 + tid;
      int row = c >> 3, s = c & 7;
      load_lds16(Bt + (size_t)(n0 + row) * DIM_ + k0 + ((s ^ (row & 7)) << 3),
                 Bs + (i * 256 + (tid & 192)) * 8);
    }
    __syncthreads();

#pragma unroll
    for (int kk = 0; kk < 2; ++kk) {
      const int kf = ((kk * 4 + g) ^ sw) << 3;
      half8_t b[4];
#pragma unroll
      for (int n = 0; n < 4; ++n)
        b[n] = *(const half8_t*)(Bs + (wn * 64 + n * 16 + lrow) * 64 + kf);
#pragma unroll
      for (int m = 0; m < 8; ++m) {
        half8_t a = *(const half8_t*)(As + (wm * 128 + m * 16 + lrow) * 64 + kf);
#pragma unroll
        for (int n = 0; n < 4; ++n)
          acc[m][n] = __builtin_amdgcn_mfma_f32_16x16x32_f16(a, b[n], acc[m][n], 0, 0, 0);
      }
    }
    __syncthreads();
  }
}

// ---------------------------------------------------------------------------
// K1: qkv = xh @ WqkvT^T, scatter into qh/kh/vh [bh][t][64] f16, q scaled.
// Staged coalesced epilogue: per-wave 64x64-row rounds via LDS transpose,
// 128B contiguous row stores.
// ---------------------------------------------------------------------------
__global__ __launch_bounds__(256) void qkv_gemm_kernel(
    const _Float16* __restrict__ xh, const _Float16* __restrict__ wqkvT,
    _Float16* __restrict__ qh, _Float16* __restrict__ kh, _Float16* __restrict__ vh) {
  __shared__ _Float16 As[256 * 64];
  __shared__ _Float16 Bs[128 * 64];
  const int nwg = 99 * 12;
  const int lin = xcd_swz(blockIdx.x, nwg);
  const int mb = lin / 12, nb = lin - mb * 12;
  const int m0 = mb * 256, n0 = nb * 128;

  f32x4 acc[8][4];
#pragma unroll
  for (int m = 0; m < 8; ++m)
#pragma unroll
    for (int n = 0; n < 4; ++n) acc[m][n] = (f32x4)0.f;

  gemm_mainloop_f16_w128(xh, wqkvT, m0, n0, M_ - 1, As, Bs, acc);
  // mainloop ends with __syncthreads(): safe to reuse As as staging.

  const int tid = threadIdx.x;
  const int w = tid >> 6, lane = tid & 63;
  const int wm = w >> 1, wn = w & 1;
  const int g = lane >> 4, lrow = lane & 15;

  _Float16* stg = As + w * 4096;            // 8KB per wave
  const int gcb0 = n0 + wn * 64;            // 64-aligned -> one head chunk
  const int which = gcb0 >> 9;
  const int h = (gcb0 >> 6) & 7;
  const float scale = (which == 0) ? 0.125f : 1.0f;
  _Float16* dst = (which == 0) ? qh : (which == 1) ? kh : vh;
  const int rl = lane >> 3, cs = lane & 7;

#pragma unroll
  for (int r0 = 0; r0 < 2; ++r0) {          // two 64-row rounds
#pragma unroll
    for (int mm = 0; mm < 4; ++mm) {
      int m = r0 * 4 + mm;
#pragma unroll
      for (int n = 0; n < 4; ++n)
#pragma unroll
        for (int j = 0; j < 4; ++j) {
          int row2 = mm * 16 + g * 4 + j;
          int col = n * 16 + lrow;
          int slot = (col >> 3) ^ (row2 & 7);
          stg[row2 * 64 + slot * 8 + (col & 7)] = (_Float16)(acc[m][n][j] * scale);
        }
    }
    asm volatile("s_waitcnt lgkmcnt(0)" ::: "memory");
    __builtin_amdgcn_sched_barrier(0);
#pragma unroll
    for (int rr = 0; rr < 8; ++rr) {
      int row2 = rr * 8 + rl;
      int grow = m0 + wm * 128 + r0 * 64 + row2;
      if (grow < M_) {
        int b = grow / SEQ_;
        int t = grow - b * SEQ_;
        half8_t v = *(const half8_t*)(stg + row2 * 64 + ((cs ^ (row2 & 7)) << 3));
        *(half8_t*)(dst + ((size_t)(b * H_ + h) * SEQ_ + t) * DH_ + cs * 8) = v;
      }
    }
    if (r0 == 0) {
      asm volatile("s_waitcnt lgkmcnt(0)" ::: "memory");
      __builtin_amdgcn_sched_barrier(0);
    }
  }
}

// ---------------------------------------------------------------------------
// K4: out = attnh @ WoutT^T + bout (fp32 out, 64B-coalesced stores).
// ---------------------------------------------------------------------------
__global__ __launch_bounds__(256) void out_gemm_kernel(
    const _Float16* __restrict__ attnh, const _Float16* __restrict__ woutT,
    const float* __restrict__ bias, float* __restrict__ out) {
  __shared__ _Float16 As[256 * 64];
  __shared__ _Float16 Bs[128 * 64];
  const int nwg = 99 * 4;
  const int lin = xcd_swz(blockIdx.x, nwg);
  const int mb = lin >> 2, nb = lin & 3;
  const int m0 = mb * 256, n0 = nb * 128;

  f32x4 acc[8][4];
#pragma unroll
  for (int m = 0; m < 8; ++m)
#pragma unroll
    for (int n = 0; n < 4; ++n) acc[m][n] = (f32x4)0.f;

  gemm_mainloop_f16_w128(attnh, woutT, m0, n0, M_ - 1, As, Bs, acc);

  const int tid = threadIdx.x;
  const int w = tid >> 6, lane = tid & 63;
  const int wm = w >> 1, wn = w & 1;
  const int g = lane >> 4, lrow = lane & 15;
#pragma unroll
  for (int n = 0; n < 4; ++n) {
    const int gcol = n0 + wn * 64 + n * 16 + lrow;
    const float bv = bias[gcol];
#pragma unroll
    for (int m = 0; m < 8; ++m)
#pragma unroll
      for (int j = 0; j < 4; ++j) {
        int grow = m0 + wm * 128 + m * 16 + g * 4 + j;
        if (grow < M_) out[(size_t)grow * DIM_ + gcol] = acc[m][n][j] + bv;
      }
  }
}

// ---------------------------------------------------------------------------
// K2+K3 fused: 1024 blocks, one per (bh, frame), 4 waves.
// Frame attention (MFMA) + CLS partial over this block's staged keys.
// ---------------------------------------------------------------------------
__global__ __launch_bounds__(256) void attn_kernel(
    const _Float16* __restrict__ qh, const _Float16* __restrict__ kh,
    const _Float16* __restrict__ vh, _Float16* __restrict__ attnh,
    float* __restrict__ clsp) {
  __shared__ _Float16 SMEM[36864];     // 73,728 B
  const int bx = blockIdx.x;
  const int tid = threadIdx.x;

  const int bh = bx >> 4, fi = bx & 15;
  const int b = bh >> 3, h = bh & 7;
  const int w = tid >> 6, lane = tid & 63;
  const int g = lane >> 4, lc = lane & 15;
  _Float16* KL = SMEM;                  // [208][64] swizzled
  _Float16* VT = SMEM + 13312;          // [64][232]
  _Float16* Pb = SMEM + 28160;          // 4 x [16][136]
  _Float16* tmp = Pb;                   // prologue alias: [104][64] swizzled
  _Float16* Pw = Pb + w * (16 * 136);

  const size_t base = (size_t)bh * SEQ_ * DH_;

  // hoisted Q loads (all 4 qt candidates for this wave)
  half8_t qb0[4], qb1[4];
#pragma unroll
  for (int it = 0; it < 4; ++it) {
    int qq = min((w + it * 4) * 16 + lc, NP_ - 1);
    const _Float16* qp = qh + base + (size_t)(1 + fi * NP_ + qq) * DH_ + g * 8;
    qb0[it] = *(const half8_t*)(qp);
    qb1[it] = *(const half8_t*)(qp + 32);
  }

  // bulk K staging: 208 rows x 64 f16, coalesced (8 lanes/row)
  for (int i = 0; i < 7; ++i) {
    int gran = i * 256 + tid;
    if (gran < 1664) {
      int row = gran >> 3, cg = gran & 7;
      int rowtok = (row == 0) ? 0 : fi * NP_ + min(row, NP_);
      load_lds16(kh + base + (size_t)rowtok * DH_ + ((cg ^ (row & 7)) << 3),
                 KL + (i * 256 + (tid & 192)) * 8);
    }
  }

  // V: stage row-major coalesced into tmp (104 rows/half), LDS-transpose to VT
#pragma unroll
  for (int half = 0; half < 2; ++half) {
    const int r0 = half * 104;
#pragma unroll
    for (int i = 0; i < 4; ++i) {
      int c = i * 256 + tid;
      if (c < 832) {
        int row = c >> 3, cg = c & 7;
        int gr = r0 + row;
        int rowtok = (gr == 0) ? 0 : fi * NP_ + min(gr, NP_);
        load_lds16(vh + base + (size_t)rowtok * DH_ + ((cg ^ (row & 7)) << 3),
                   tmp + (i * 256 + (tid & 192)) * 8);
      }
    }
    if (half == 1) {
      for (int idx = tid; idx < 64 * 35; idx += 256) {
        int d = idx / 35;
        VT[d * 232 + 197 + (idx - d * 35)] = (_Float16)0.f;
      }
    }
    __syncthreads();   // drains staging into tmp (and K on first pass)
#pragma unroll
    for (int i = 0; i < 4; ++i) {
      int item = i * 256 + tid;
      if (item < 832) {
        int cg = item / 104;
        int key = item - cg * 104;
        int gk = r0 + key;
        if (gk <= 196) {
          half8_t v = *(const half8_t*)(tmp + key * 64 + ((cg ^ (key & 7)) << 3));
#pragma unroll
          for (int u = 0; u < 8; ++u) VT[(cg * 8 + u) * 232 + gk] = v[u];
        }
      }
    }
    __syncthreads();   // transpose done before tmp reuse / P use
  }

  const f32x4 zero4 = (f32x4)0.f;

#pragma unroll
  for (int it = 0; it < 4; ++it) {
    const int qt = w + it * 4;
    if (qt < 13) {
      f32x4 st[13];
#pragma unroll
      for (int t = 0; t < 13; ++t) {
        int key = t * 16 + lc;
        const _Float16* kp = KL + key * 64;
        half8_t ka0 = *(const half8_t*)(kp + ((g ^ (key & 7)) << 3));
        half8_t ka1 = *(const half8_t*)(kp + (((4 + g) ^ (key & 7)) << 3));
        st[t] = __builtin_amdgcn_mfma_f32_16x16x32_f16(ka0, qb0[it], zero4, 0, 0, 0);
        st[t] = __builtin_amdgcn_mfma_f32_16x16x32_f16(ka1, qb1[it], st[t], 0, 0, 0);
      }

      float mx = -1e30f;
#pragma unroll
      for (int t = 0; t < 13; ++t)
#pragma unroll
        for (int j = 0; j < 4; ++j) {
          int key = t * 16 + g * 4 + j;
          if (key >= 197) st[t][j] = -1e30f;
          mx = fmaxf(mx, st[t][j]);
        }
      mx = fmaxf(mx, __shfl_xor(mx, 16));
      mx = fmaxf(mx, __shfl_xor(mx, 32));
      float l = 0.f;
#pragma unroll
      for (int t = 0; t < 13; ++t)
#pragma unroll
        for (int j = 0; j < 4; ++j) {
          float p = __expf(st[t][j] - mx);
          st[t][j] = p;
          l += p;
        }
      l += __shfl_xor(l, 16);
      l += __shfl_xor(l, 32);
      const float inv = 1.f / l;

      f32x4 o[4];
#pragma unroll
      for (int dt = 0; dt < 4; ++dt) o[dt] = zero4;

      // ---- half A: P tiles 0..7 (keys 0..127), stride 136 ----
#pragma unroll
      for (int t = 0; t < 8; ++t) {
        half4_t hp;
#pragma unroll
        for (int j = 0; j < 4; ++j) hp[j] = (_Float16)(st[t][j] * inv);
        *(half4_t*)(Pw + lc * 136 + t * 16 + g * 4) = hp;
      }
#pragma unroll
      for (int c = 0; c < 4; ++c) {
        half8_t pa = *(const half8_t*)(Pw + lc * 136 + c * 32 + g * 8);
#pragma unroll
        for (int dt = 0; dt < 4; ++dt) {
          half8_t vb = *(const half8_t*)(VT + (dt * 16 + lc) * 232 + c * 32 + g * 8);
          o[dt] = __builtin_amdgcn_mfma_f32_16x16x32_f16(pa, vb, o[dt], 0, 0, 0);
        }
      }

      // ---- half B: P tiles 8..12 + zero tile (keys 128..223), stride 104 ----
#pragma unroll
      for (int t = 8; t < 13; ++t) {
        half4_t hp;
#pragma unroll
        for (int j = 0; j < 4; ++j) hp[j] = (_Float16)(st[t][j] * inv);
        *(half4_t*)(Pw + lc * 104 + (t - 8) * 16 + g * 4) = hp;
      }
      {
        half4_t hz;
#pragma unroll
        for (int j = 0; j < 4; ++j) hz[j] = (_Float16)0.f;
        *(half4_t*)(Pw + lc * 104 + 80 + g * 4) = hz;   // keys 208..223
      }
#pragma unroll
      for (int c = 4; c < 7; ++c) {
        half8_t pa = *(const half8_t*)(Pw + lc * 104 + (c - 4) * 32 + g * 8);
#pragma unroll
        for (int dt = 0; dt < 4; ++dt) {
          half8_t vb = *(const half8_t*)(VT + (dt * 16 + lc) * 232 + c * 32 + g * 8);
          o[dt] = __builtin_amdgcn_mfma_f32_16x16x32_f16(pa, vb, o[dt], 0, 0, 0);
        }
      }

#pragma unroll
      for (int dt = 0; dt < 4; ++dt)
#pragma unroll
        for (int j = 0; j < 4; ++j) {
          int q = qt * 16 + g * 4 + j;
          if (q < NP_) {
            int tok = 1 + fi * NP_ + q;
            attnh[((size_t)(b * SEQ_) + tok) * DIM_ + h * DH_ + dt * 16 + lc] =
                (_Float16)o[dt][j];
          }
        }
    }
  }

  // ---------------- CLS partial over this block's staged keys ----------------
  __syncthreads();                       // all waves done with Pb; KL/VT stable
  float* qs  = (float*)Pb;               // [64]
  float* pp  = qs + 64;                  // [256]
  float* red = pp + 256;                 // [256]
  if (tid < 64) qs[tid] = (float)qh[base + tid];  // CLS q row (token 0, scaled)
  __syncthreads();

  const int kmin = (fi == 0) ? 0 : 1;    // CLS key only counted in block fi=0
  float sc = -1e30f;
  if (tid >= kmin && tid < 197) {
    float s = 0.f;
#pragma unroll
    for (int i = 0; i < 8; ++i) {
      half8_t kk = *(const half8_t*)(KL + tid * 64 + ((i ^ (tid & 7)) << 3));
#pragma unroll
      for (int u = 0; u < 8; ++u) s += qs[8 * i + u] * (float)kk[u];
    }
    sc = s;
  }
  red[tid] = sc; __syncthreads();
  for (int st = 128; st > 0; st >>= 1) {
    if (tid < st) red[tid] = fmaxf(red[tid], red[tid + st]);
    __syncthreads();
  }
  const float cm = red[0]; __syncthreads();

  float cp = (tid >= kmin && tid < 197) ? __expf(sc - cm) : 0.f;
  pp[tid] = cp;
  red[tid] = cp; __syncthreads();
  for (int st = 128; st > 0; st >>= 1) {
    if (tid < st) red[tid] += red[tid + st];
    __syncthreads();
  }
  const float clsum = red[0]; __syncthreads();

  const int d = tid & 63;
  float a = 0.f;
#pragma unroll 4
  for (int u = 0; u < 64; ++u) {
    int k = w * 64 + u;
    if (k <= 196) a += pp[k] * (float)VT[d * 232 + k];
  }
  red[tid] = a; __syncthreads();
  if (tid < 64) {
    float asum = red[tid] + red[64 + tid] + red[128 + tid] + red[192 + tid];
    float* P = clsp + (size_t)(bh * 16 + fi) * 72;
    P[tid] = asum;
    if (tid == 0) { P[64] = cm; P[65] = clsum; }
  }
}

// ---------------------------------------------------------------------------
// CLS combine: merge 16 per-frame partials per (b,h) -> attnh CLS row.
// ---------------------------------------------------------------------------
__global__ __launch_bounds__(64) void cls_combine_kernel(
    const float* __restrict__ clsp, _Float16* __restrict__ attnh) {
  const int bh = blockIdx.x;
  const int b = bh >> 3, h = bh & 7;
  const int d = threadIdx.x;
  const float* P = clsp + (size_t)bh * 16 * 72;

  float m = -1e30f;
#pragma unroll
  for (int c = 0; c < 16; ++c) m = fmaxf(m, P[c * 72 + 64]);
  float l = 0.f, o = 0.f;
#pragma unroll
  for (int c = 0; c < 16; ++c) {
    float wgt = __expf(P[c * 72 + 64] - m);
    l += P[c * 72 + 65] * wgt;
    o += P[c * 72 + d] * wgt;
  }
  attnh[(size_t)(b * SEQ_) * DIM_ + h * DH_ + d] = (_Float16)(o / l);
}

// ---------------------------------------------------------------------------
extern "C" void kernel_launch(void* const* d_in, const int* in_sizes, int n_in,
                              void* d_out, int out_size, void* d_ws, size_t ws_size,
                              hipStream_t stream) {
  (void)in_sizes; (void)n_in; (void)out_size; (void)ws_size;
  const float* x    = (const float*)d_in[0];
  const float* wqkv = (const float*)d_in[1];
  const float* wout = (const float*)d_in[2];
  const float* bout = (const float*)d_in[3];
  char* ws = (char*)d_ws;
  _Float16* xh    = (_Float16*)(ws + XH_OFF);
  _Float16* wqkvT = (_Float16*)(ws + WQKVT_OFF);
  _Float16* woutT = (_Float16*)(ws + WOUTT_OFF);
  _Float16* qh    = (_Float16*)(ws + QH_OFF);
  _Float16* kh    = (_Float16*)(ws + KH_OFF);
  _Float16* vh    = (_Float16*)(ws + VH_OFF);
  _Float16* attnh = (_Float16*)(ws + ATTNH_OFF);
  float*    clsp  = (float*)(ws + CLSP_OFF);   // aliases xh (dead after qkv)
  float* out = (float*)d_out;

  prep_kernel<<<3072, 256, 0, stream>>>(x, xh, wqkv, wqkvT, wout, woutT);

  qkv_gemm_kernel<<<99 * 12, 256, 0, stream>>>(xh, wqkvT, qh, kh, vh);

  attn_kernel<<<BH_ * F_, 256, 0, stream>>>(qh, kh, vh, attnh, clsp);
  cls_combine_kernel<<<BH_, 64, 0, stream>>>(clsp, attnh);

  out_gemm_kernel<<<99 * 4, 256, 0, stream>>>(attnh, woutT, bout, out);
}

// Round 14
// 163.977 us; speedup vs baseline: 1.2859x; 1.2859x over previous
//
#include <hip/hip_runtime.h>
#include <hip/hip_bf16.h>

// Problem constants
#define B_    8
#define F_    16
#define NP_   196
#define SEQ_  3137        // 1 + F_*NP_
#define H_    8
#define DH_   64
#define BH_   64          // B_*H_
#define M_    25096       // B_*SEQ_
#define DIM_  512
#define NQKV_ 1536

typedef _Float16 half8_t __attribute__((ext_vector_type(8)));
typedef _Float16 half4_t __attribute__((ext_vector_type(4)));
typedef float f32x4 __attribute__((ext_vector_type(4)));

// workspace byte offsets
#define XH_OFF     ((size_t)0)                    // [M][512] f16
#define WQKVT_OFF  ((size_t)25821184)             // [1536][512] f16
#define WOUTT_OFF  ((size_t)27394048)             // [512][512]  f16
#define QH_OFF     ((size_t)27918336)             // [64][3137][64] f16
#define KH_OFF     ((size_t)53616640)
#define VH_OFF     ((size_t)79314944)
#define ATTNH_OFF  ((size_t)105013248)            // [M][512] f16
#define CLSP_OFF   XH_OFF                         // aliases xh (dead after qkv)

__device__ __forceinline__ void load_lds16(const _Float16* g, _Float16* l) {
  __builtin_amdgcn_global_load_lds(
      (const __attribute__((address_space(1))) void*)g,
      (__attribute__((address_space(3))) void*)l, 16, 0, 0);
}

// bijective XCD-chunk swizzle (m204)
__device__ __forceinline__ int xcd_swz(int orig, int nwg) {
  int q = nwg >> 3, r = nwg & 7;
  int x = orig & 7, j = orig >> 3;
  return (x < r ? x * (q + 1) : r * (q + 1) + (x - r) * q) + j;
}

// ---------------------------------------------------------------------------
// prep: blocks 0..1023 = weight transposes (fp32->f16 [C][512]);
//       blocks 1024..3071 = x fp32->f16 convert.
// ---------------------------------------------------------------------------
__global__ __launch_bounds__(256) void prep_kernel(
    const float* __restrict__ x, _Float16* __restrict__ xh,
    const float* __restrict__ wqkv, _Float16* __restrict__ wqkvT,
    const float* __restrict__ wout, _Float16* __restrict__ woutT) {
  if (blockIdx.x < 1024) {
    __shared__ float tile[32][33];
    int id = blockIdx.x;
    int xb = id & 15, by = id >> 4;
    const float* in; _Float16* out; int C;
    if (by < 48) { in = wqkv; out = wqkvT; C = NQKV_; }
    else         { in = wout; out = woutT; C = DIM_;  by -= 48; }
    const int r0 = xb * 32, c0 = by * 32;
    const int lr = threadIdx.x >> 5, lc = threadIdx.x & 31;
#pragma unroll
    for (int p = 0; p < 4; ++p) {
      int r = p * 8 + lr;
      tile[r][lc] = in[(size_t)(r0 + r) * C + c0 + lc];
    }
    __syncthreads();
#pragma unroll
    for (int p = 0; p < 4; ++p) {
      int rr = p * 8 + lr;
      out[(size_t)(c0 + rr) * DIM_ + r0 + lc] = (_Float16)tile[lc][rr];
    }
    return;
  }
  const int id = blockIdx.x - 1024;  // 0..2047
  const size_t n8 = (size_t)M_ * DIM_ / 8;
  for (size_t i = (size_t)id * 256 + threadIdx.x; i < n8;
       i += (size_t)2048 * 256) {
    float4 a = ((const float4*)x)[2 * i];
    float4 b = ((const float4*)x)[2 * i + 1];
    half8_t h;
    h[0] = (_Float16)a.x; h[1] = (_Float16)a.y; h[2] = (_Float16)a.z; h[3] = (_Float16)a.w;
    h[4] = (_Float16)b.x; h[5] = (_Float16)b.y; h[6] = (_Float16)b.z; h[7] = (_Float16)b.w;
    ((half8_t*)xh)[i] = h;
  }
}

// ---------------------------------------------------------------------------
// shared f16 MFMA mainloop: 128x128 tile, BK=64, 256 threads (4 waves 2x2).
// LDS XOR-swizzled: linear global_load_lds dest + pre-swizzled global source
// col; frag reads XOR (row&7)<<3. (Best-measured structure: R7/R12.)
// ---------------------------------------------------------------------------
__device__ __forceinline__ void gemm_mainloop_f16(
    const _Float16* __restrict__ A, const _Float16* __restrict__ Bt,
    int m0, int n0, _Float16* As, _Float16* Bs, f32x4 acc[4][4]) {
  const int tid = threadIdx.x;
  const int w = tid >> 6, lane = tid & 63;
  const int wr = w >> 1, wc = w & 1;
  const int lrow = lane & 15;
  const int g = lane >> 4;
  const int sw = lane & 7;

  const int srow = lane >> 3;
  const int scol = ((lane & 7) ^ srow) << 3;

  for (int k0 = 0; k0 < DIM_; k0 += 64) {
#pragma unroll
    for (int i = 0; i < 4; ++i) {
      int c = w * 4 + i;
      int r = c * 8 + srow;
      load_lds16(A + (size_t)(m0 + r) * DIM_ + k0 + scol, As + c * 512);
      load_lds16(Bt + (size_t)(n0 + r) * DIM_ + k0 + scol, Bs + c * 512);
    }
    __syncthreads();

#pragma unroll
    for (int kk = 0; kk < 2; ++kk) {
      const int kf = ((kk * 4 + g) ^ sw) << 3;
      half8_t a[4], b[4];
#pragma unroll
      for (int m = 0; m < 4; ++m)
        a[m] = *(const half8_t*)(As + (wr * 64 + m * 16 + lrow) * 64 + kf);
#pragma unroll
      for (int n = 0; n < 4; ++n)
        b[n] = *(const half8_t*)(Bs + (wc * 64 + n * 16 + lrow) * 64 + kf);
#pragma unroll
      for (int m = 0; m < 4; ++m)
#pragma unroll
        for (int n = 0; n < 4; ++n)
          acc[m][n] = __builtin_amdgcn_mfma_f32_16x16x32_f16(a[m], b[n], acc[m][n], 0, 0, 0);
    }
    __syncthreads();
  }
}

// ---------------------------------------------------------------------------
// K1: qkv = xh @ WqkvT^T, scatter into qh/kh/vh [bh][t][64] f16, q scaled.
// Staged coalesced epilogue (LDS transpose, 128B row stores).
// ---------------------------------------------------------------------------
__global__ __launch_bounds__(256) void qkv_gemm_kernel(
    const _Float16* __restrict__ xh, const _Float16* __restrict__ wqkvT,
    _Float16* __restrict__ qh, _Float16* __restrict__ kh, _Float16* __restrict__ vh) {
  __shared__ _Float16 As[128 * 64];
  __shared__ _Float16 Bs[128 * 64];
  const int nwg = 197 * 12;
  const int lin = xcd_swz(blockIdx.x, nwg);
  const int mb = lin / 12, nb = lin - mb * 12;
  const int m0 = mb * 128, n0 = nb * 128;

  f32x4 acc[4][4];
#pragma unroll
  for (int m = 0; m < 4; ++m)
#pragma unroll
    for (int n = 0; n < 4; ++n) acc[m][n] = (f32x4)0.f;

  gemm_mainloop_f16(xh, wqkvT, m0, n0, As, Bs, acc);
  // mainloop ends with __syncthreads(): safe to reuse As/Bs as staging.

  const int tid = threadIdx.x;
  const int w = tid >> 6, lane = tid & 63;
  const int wr = w >> 1, wc = w & 1;
  const int g = lane >> 4, lrow = lane & 15;

  _Float16* stg = (w < 2) ? (As + w * 4096) : (Bs + (w - 2) * 4096);
  const int gcb0 = n0 + wc * 64;            // 64-aligned -> one head chunk
  const int which = gcb0 >> 9;
  const int h = (gcb0 >> 6) & 7;
  const float scale = (which == 0) ? 0.125f : 1.0f;
  _Float16* dst = (which == 0) ? qh : (which == 1) ? kh : vh;

#pragma unroll
  for (int m = 0; m < 4; ++m)
#pragma unroll
    for (int n = 0; n < 4; ++n)
#pragma unroll
      for (int j = 0; j < 4; ++j) {
        int row = m * 16 + g * 4 + j;
        int col = n * 16 + lrow;
        int slot = (col >> 3) ^ (row & 7);
        stg[row * 64 + slot * 8 + (col & 7)] = (_Float16)(acc[m][n][j] * scale);
      }
  asm volatile("s_waitcnt lgkmcnt(0)" ::: "memory");
  __builtin_amdgcn_sched_barrier(0);

  const int rl = lane >> 3, cs = lane & 7;
#pragma unroll
  for (int rr = 0; rr < 8; ++rr) {
    int row = rr * 8 + rl;
    int grow = m0 + wr * 64 + row;
    if (grow < M_) {
      int b = grow / SEQ_;
      int t = grow - b * SEQ_;
      half8_t v = *(const half8_t*)(stg + row * 64 + ((cs ^ (row & 7)) << 3));
      *(half8_t*)(dst + ((size_t)(b * H_ + h) * SEQ_ + t) * DH_ + cs * 8) = v;
    }
  }
}

// ---------------------------------------------------------------------------
// K4: out = attnh @ WoutT^T + bout (fp32 out, 64B-coalesced stores).
// ---------------------------------------------------------------------------
__global__ __launch_bounds__(256) void out_gemm_kernel(
    const _Float16* __restrict__ attnh, const _Float16* __restrict__ woutT,
    const float* __restrict__ bias, float* __restrict__ out) {
  __shared__ _Float16 As[128 * 64];
  __shared__ _Float16 Bs[128 * 64];
  const int nwg = 197 * 4;
  const int lin = xcd_swz(blockIdx.x, nwg);
  const int mb = lin >> 2, nb = lin & 3;
  const int m0 = mb * 128, n0 = nb * 128;

  f32x4 acc[4][4];
#pragma unroll
  for (int m = 0; m < 4; ++m)
#pragma unroll
    for (int n = 0; n < 4; ++n) acc[m][n] = (f32x4)0.f;

  gemm_mainloop_f16(attnh, woutT, m0, n0, As, Bs, acc);

  const int tid = threadIdx.x;
  const int w = tid >> 6, lane = tid & 63;
  const int wr = w >> 1, wc = w & 1;
#pragma unroll
  for (int n = 0; n < 4; ++n) {
    const int gcol = n0 + wc * 64 + n * 16 + (lane & 15);
    const float bv = bias[gcol];
#pragma unroll
    for (int m = 0; m < 4; ++m)
#pragma unroll
      for (int j = 0; j < 4; ++j) {
        int grow = m0 + wr * 64 + m * 16 + (lane >> 4) * 4 + j;
        if (grow < M_) out[(size_t)grow * DIM_ + gcol] = acc[m][n][j] + bv;
      }
  }
}

// ---------------------------------------------------------------------------
// K2+K3 fused: 1024 blocks, one per (bh, frame), 4 waves.
// Frame attention (MFMA) + CLS partial over this block's staged keys.
// ---------------------------------------------------------------------------
__global__ __launch_bounds__(256) void attn_kernel(
    const _Float16* __restrict__ qh, const _Float16* __restrict__ kh,
    const _Float16* __restrict__ vh, _Float16* __restrict__ attnh,
    float* __restrict__ clsp) {
  __shared__ _Float16 SMEM[36864];     // 73,728 B
  const int bx = blockIdx.x;
  const int tid = threadIdx.x;

  const int bh = bx >> 4, fi = bx & 15;
  const int b = bh >> 3, h = bh & 7;
  const int w = tid >> 6, lane = tid & 63;
  const int g = lane >> 4, lc = lane & 15;
  _Float16* KL = SMEM;                  // [208][64] swizzled
  _Float16* VT = SMEM + 13312;          // [64][232]
  _Float16* Pb = SMEM + 28160;          // 4 x [16][136]
  _Float16* tmp = Pb;                   // prologue alias: [104][64] swizzled
  _Float16* Pw = Pb + w * (16 * 136);

  const size_t base = (size_t)bh * SEQ_ * DH_;

  // hoisted Q loads (all 4 qt candidates for this wave)
  half8_t qb0[4], qb1[4];
#pragma unroll
  for (int it = 0; it < 4; ++it) {
    int qq = min((w + it * 4) * 16 + lc, NP_ - 1);
    const _Float16* qp = qh + base + (size_t)(1 + fi * NP_ + qq) * DH_ + g * 8;
    qb0[it] = *(const half8_t*)(qp);
    qb1[it] = *(const half8_t*)(qp + 32);
  }

  // bulk K staging: 208 rows x 64 f16, coalesced (8 lanes/row)
  for (int i = 0; i < 7; ++i) {
    int gran = i * 256 + tid;
    if (gran < 1664) {
      int row = gran >> 3, cg = gran & 7;
      int rowtok = (row == 0) ? 0 : fi * NP_ + min(row, NP_);
      load_lds16(kh + base + (size_t)rowtok * DH_ + ((cg ^ (row & 7)) << 3),
                 KL + (i * 256 + (tid & 192)) * 8);
    }
  }

  // V: stage row-major coalesced into tmp (104 rows/half), LDS-transpose to VT
#pragma unroll
  for (int half = 0; half < 2; ++half) {
    const int r0 = half * 104;
#pragma unroll
    for (int i = 0; i < 4; ++i) {
      int c = i * 256 + tid;
      if (c < 832) {
        int row = c >> 3, cg = c & 7;
        int gr = r0 + row;
        int rowtok = (gr == 0) ? 0 : fi * NP_ + min(gr, NP_);
        load_lds16(vh + base + (size_t)rowtok * DH_ + ((cg ^ (row & 7)) << 3),
                   tmp + (i * 256 + (tid & 192)) * 8);
      }
    }
    if (half == 1) {
      for (int idx = tid; idx < 64 * 35; idx += 256) {
        int d = idx / 35;
        VT[d * 232 + 197 + (idx - d * 35)] = (_Float16)0.f;
      }
    }
    __syncthreads();   // drains staging into tmp (and K on first pass)
#pragma unroll
    for (int i = 0; i < 4; ++i) {
      int item = i * 256 + tid;
      if (item < 832) {
        int cg = item / 104;
        int key = item - cg * 104;
        int gk = r0 + key;
        if (gk <= 196) {
          half8_t v = *(const half8_t*)(tmp + key * 64 + ((cg ^ (key & 7)) << 3));
#pragma unroll
          for (int u = 0; u < 8; ++u) VT[(cg * 8 + u) * 232 + gk] = v[u];
        }
      }
    }
    __syncthreads();   // transpose done before tmp reuse / P use
  }

  const f32x4 zero4 = (f32x4)0.f;

#pragma unroll
  for (int it = 0; it < 4; ++it) {
    const int qt = w + it * 4;
    if (qt < 13) {
      f32x4 st[13];
#pragma unroll
      for (int t = 0; t < 13; ++t) {
        int key = t * 16 + lc;
        const _Float16* kp = KL + key * 64;
        half8_t ka0 = *(const half8_t*)(kp + ((g ^ (key & 7)) << 3));
        half8_t ka1 = *(const half8_t*)(kp + (((4 + g) ^ (key & 7)) << 3));
        st[t] = __builtin_amdgcn_mfma_f32_16x16x32_f16(ka0, qb0[it], zero4, 0, 0, 0);
        st[t] = __builtin_amdgcn_mfma_f32_16x16x32_f16(ka1, qb1[it], st[t], 0, 0, 0);
      }

      float mx = -1e30f;
#pragma unroll
      for (int t = 0; t < 13; ++t)
#pragma unroll
        for (int j = 0; j < 4; ++j) {
          int key = t * 16 + g * 4 + j;
          if (key >= 197) st[t][j] = -1e30f;
          mx = fmaxf(mx, st[t][j]);
        }
      mx = fmaxf(mx, __shfl_xor(mx, 16));
      mx = fmaxf(mx, __shfl_xor(mx, 32));
      float l = 0.f;
#pragma unroll
      for (int t = 0; t < 13; ++t)
#pragma unroll
        for (int j = 0; j < 4; ++j) {
          float p = __expf(st[t][j] - mx);
          st[t][j] = p;
          l += p;
        }
      l += __shfl_xor(l, 16);
      l += __shfl_xor(l, 32);
      const float inv = 1.f / l;

      f32x4 o[4];
#pragma unroll
      for (int dt = 0; dt < 4; ++dt) o[dt] = zero4;

      // ---- half A: P tiles 0..7 (keys 0..127), stride 136 ----
#pragma unroll
      for (int t = 0; t < 8; ++t) {
        half4_t hp;
#pragma unroll
        for (int j = 0; j < 4; ++j) hp[j] = (_Float16)(st[t][j] * inv);
        *(half4_t*)(Pw + lc * 136 + t * 16 + g * 4) = hp;
      }
#pragma unroll
      for (int c = 0; c < 4; ++c) {
        half8_t pa = *(const half8_t*)(Pw + lc * 136 + c * 32 + g * 8);
#pragma unroll
        for (int dt = 0; dt < 4; ++dt) {
          half8_t vb = *(const half8_t*)(VT + (dt * 16 + lc) * 232 + c * 32 + g * 8);
          o[dt] = __builtin_amdgcn_mfma_f32_16x16x32_f16(pa, vb, o[dt], 0, 0, 0);
        }
      }

      // ---- half B: P tiles 8..12 + zero tile (keys 128..223), stride 104 ----
#pragma unroll
      for (int t = 8; t < 13; ++t) {
        half4_t hp;
#pragma unroll
        for (int j = 0; j < 4; ++j) hp[j] = (_Float16)(st[t][j] * inv);
        *(half4_t*)(Pw + lc * 104 + (t - 8) * 16 + g * 4) = hp;
      }
      {
        half4_t hz;
#pragma unroll
        for (int j = 0; j < 4; ++j) hz[j] = (_Float16)0.f;
        *(half4_t*)(Pw + lc * 104 + 80 + g * 4) = hz;   // keys 208..223
      }
#pragma unroll
      for (int c = 4; c < 7; ++c) {
        half8_t pa = *(const half8_t*)(Pw + lc * 104 + (c - 4) * 32 + g * 8);
#pragma unroll
        for (int dt = 0; dt < 4; ++dt) {
          half8_t vb = *(const half8_t*)(VT + (dt * 16 + lc) * 232 + c * 32 + g * 8);
          o[dt] = __builtin_amdgcn_mfma_f32_16x16x32_f16(pa, vb, o[dt], 0, 0, 0);
        }
      }

#pragma unroll
      for (int dt = 0; dt < 4; ++dt)
#pragma unroll
        for (int j = 0; j < 4; ++j) {
          int q = qt * 16 + g * 4 + j;
          if (q < NP_) {
            int tok = 1 + fi * NP_ + q;
            attnh[((size_t)(b * SEQ_) + tok) * DIM_ + h * DH_ + dt * 16 + lc] =
                (_Float16)o[dt][j];
          }
        }
    }
  }

  // ---------------- CLS partial over this block's staged keys ----------------
  __syncthreads();                       // all waves done with Pb; KL/VT stable
  float* qs  = (float*)Pb;               // [64]
  float* pp  = qs + 64;                  // [256]
  float* red = pp + 256;                 // [256]
  if (tid < 64) qs[tid] = (float)qh[base + tid];  // CLS q row (token 0, scaled)
  __syncthreads();

  const int kmin = (fi == 0) ? 0 : 1;    // CLS key only counted in block fi=0
  float sc = -1e30f;
  if (tid >= kmin && tid < 197) {
    float s = 0.f;
#pragma unroll
    for (int i = 0; i < 8; ++i) {
      half8_t kk = *(const half8_t*)(KL + tid * 64 + ((i ^ (tid & 7)) << 3));
#pragma unroll
      for (int u = 0; u < 8; ++u) s += qs[8 * i + u] * (float)kk[u];
    }
    sc = s;
  }
  red[tid] = sc; __syncthreads();
  for (int st = 128; st > 0; st >>= 1) {
    if (tid < st) red[tid] = fmaxf(red[tid], red[tid + st]);
    __syncthreads();
  }
  const float cm = red[0]; __syncthreads();

  float cp = (tid >= kmin && tid < 197) ? __expf(sc - cm) : 0.f;
  pp[tid] = cp;
  red[tid] = cp; __syncthreads();
  for (int st = 128; st > 0; st >>= 1) {
    if (tid < st) red[tid] += red[tid + st];
    __syncthreads();
  }
  const float clsum = red[0]; __syncthreads();

  const int d = tid & 63;
  float a = 0.f;
#pragma unroll 4
  for (int u = 0; u < 64; ++u) {
    int k = w * 64 + u;
    if (k <= 196) a += pp[k] * (float)VT[d * 232 + k];
  }
  red[tid] = a; __syncthreads();
  if (tid < 64) {
    float asum = red[tid] + red[64 + tid] + red[128 + tid] + red[192 + tid];
    float* P = clsp + (size_t)(bh * 16 + fi) * 72;
    P[tid] = asum;
    if (tid == 0) { P[64] = cm; P[65] = clsum; }
  }
}

// ---------------------------------------------------------------------------
// CLS combine: merge 16 per-frame partials per (b,h) -> attnh CLS row.
// ---------------------------------------------------------------------------
__global__ __launch_bounds__(64) void cls_combine_kernel(
    const float* __restrict__ clsp, _Float16* __restrict__ attnh) {
  const int bh = blockIdx.x;
  const int b = bh >> 3, h = bh & 7;
  const int d = threadIdx.x;
  const float* P = clsp + (size_t)bh * 16 * 72;

  float m = -1e30f;
#pragma unroll
  for (int c = 0; c < 16; ++c) m = fmaxf(m, P[c * 72 + 64]);
  float l = 0.f, o = 0.f;
#pragma unroll
  for (int c = 0; c < 16; ++c) {
    float wgt = __expf(P[c * 72 + 64] - m);
    l += P[c * 72 + 65] * wgt;
    o += P[c * 72 + d] * wgt;
  }
  attnh[(size_t)(b * SEQ_) * DIM_ + h * DH_ + d] = (_Float16)(o / l);
}

// ---------------------------------------------------------------------------
extern "C" void kernel_launch(void* const* d_in, const int* in_sizes, int n_in,
                              void* d_out, int out_size, void* d_ws, size_t ws_size,
                              hipStream_t stream) {
  (void)in_sizes; (void)n_in; (void)out_size; (void)ws_size;
  const float* x    = (const float*)d_in[0];
  const float* wqkv = (const float*)d_in[1];
  const float* wout = (const float*)d_in[2];
  const float* bout = (const float*)d_in[3];
  char* ws = (char*)d_ws;
  _Float16* xh    = (_Float16*)(ws + XH_OFF);
  _Float16* wqkvT = (_Float16*)(ws + WQKVT_OFF);
  _Float16* woutT = (_Float16*)(ws + WOUTT_OFF);
  _Float16* qh    = (_Float16*)(ws + QH_OFF);
  _Float16* kh    = (_Float16*)(ws + KH_OFF);
  _Float16* vh    = (_Float16*)(ws + VH_OFF);
  _Float16* attnh = (_Float16*)(ws + ATTNH_OFF);
  float*    clsp  = (float*)(ws + CLSP_OFF);   // aliases xh (dead after qkv)
  float* out = (float*)d_out;

  prep_kernel<<<3072, 256, 0, stream>>>(x, xh, wqkv, wqkvT, wout, woutT);

  qkv_gemm_kernel<<<197 * 12, 256, 0, stream>>>(xh, wqkvT, qh, kh, vh);

  attn_kernel<<<BH_ * F_, 256, 0, stream>>>(qh, kh, vh, attnh, clsp);
  cls_combine_kernel<<<BH_, 64, 0, stream>>>(clsp, attnh);

  out_gemm_kernel<<<197 * 4, 256, 0, stream>>>(attnh, woutT, bout, out);
}